// Round 3
// baseline (1843.393 us; speedup 1.0000x reference)
//
#include <hip/hip_runtime.h>
#include <math.h>

#define B_ 16
#define C_ 512
#define NPIX 4096
#define WW 64
#define CQK 64
#define CV 256
#define MP 1024
#define NEG_BIG (-1e30f)

// out[b][n][o] = sum_c W[o][c] * x[b][c][n]
// grid (NPIX/64, Cout/64, B), block 256
__global__ __launch_bounds__(256) void proj_kernel(
    const float* __restrict__ x, const float* __restrict__ W,
    float* __restrict__ outp, int Cout)
{
  __shared__ float xs[32][68];   // [c][n]
  __shared__ float wsh[32][68];  // [c][o]
  const int n0 = blockIdx.x * 64;
  const int o0 = blockIdx.y * 64;
  const int b  = blockIdx.z;
  const int t  = threadIdx.x;
  const int tn = t & 15, to = t >> 4;
  const float* xb = x + (size_t)b * C_ * NPIX;
  float acc[4][4] = {};
  for (int c0 = 0; c0 < C_; c0 += 32) {
    const int cc = t >> 4;
    const int nn = (t & 15) << 2;
    float4 v0 = *(const float4*)(xb + (size_t)(c0 + cc) * NPIX + (n0 + nn));
    float4 v1 = *(const float4*)(xb + (size_t)(c0 + cc + 16) * NPIX + (n0 + nn));
    const int oo  = t >> 3;
    const int cc0 = (t & 7) << 2;
    float4 w0 = *(const float4*)(W + (size_t)(o0 + oo) * C_ + (c0 + cc0));
    float4 w1 = *(const float4*)(W + (size_t)(o0 + oo + 32) * C_ + (c0 + cc0));
    *(float4*)&xs[cc][nn] = v0;
    *(float4*)&xs[cc + 16][nn] = v1;
    wsh[cc0 + 0][oo] = w0.x; wsh[cc0 + 1][oo] = w0.y;
    wsh[cc0 + 2][oo] = w0.z; wsh[cc0 + 3][oo] = w0.w;
    wsh[cc0 + 0][oo + 32] = w1.x; wsh[cc0 + 1][oo + 32] = w1.y;
    wsh[cc0 + 2][oo + 32] = w1.z; wsh[cc0 + 3][oo + 32] = w1.w;
    __syncthreads();
    #pragma unroll
    for (int k = 0; k < 32; ++k) {
      float4 xv = *(const float4*)&xs[k][tn << 2];
      float4 wv = *(const float4*)&wsh[k][to << 2];
      acc[0][0] += wv.x * xv.x; acc[0][1] += wv.x * xv.y; acc[0][2] += wv.x * xv.z; acc[0][3] += wv.x * xv.w;
      acc[1][0] += wv.y * xv.x; acc[1][1] += wv.y * xv.y; acc[1][2] += wv.y * xv.z; acc[1][3] += wv.y * xv.w;
      acc[2][0] += wv.z * xv.x; acc[2][1] += wv.z * xv.y; acc[2][2] += wv.z * xv.z; acc[2][3] += wv.z * xv.w;
      acc[3][0] += wv.w * xv.x; acc[3][1] += wv.w * xv.y; acc[3][2] += wv.w * xv.z; acc[3][3] += wv.w * xv.w;
    }
    __syncthreads();
  }
  float* ob = outp + ((size_t)b * NPIX + n0) * Cout + o0;
  #pragma unroll
  for (int ni = 0; ni < 4; ++ni) {
    float4 r = make_float4(acc[0][ni], acc[1][ni], acc[2][ni], acc[3][ni]);
    *(float4*)(ob + (size_t)((tn << 2) + ni) * Cout + (to << 2)) = r;
  }
}

// inp [B][NPIX][Cout] -> outp [B][MP][Cout], 2x2 spatial max
__global__ __launch_bounds__(256) void pool_kernel(
    const float* __restrict__ inp, float* __restrict__ outp, int Cout)
{
  size_t id = (size_t)blockIdx.x * 256 + threadIdx.x;
  int o = (int)(id % Cout);
  int m = (int)((id / Cout) % MP);
  int b = (int)(id / ((size_t)Cout * MP));
  if (b >= B_) return;
  int mi = m >> 5, mj = m & 31;
  const float* base = inp + (size_t)b * NPIX * Cout;
  int n00 = (mi * 2) * WW + mj * 2;
  float v = fmaxf(
      fmaxf(base[(size_t)n00 * Cout + o], base[(size_t)(n00 + 1) * Cout + o]),
      fmaxf(base[(size_t)(n00 + WW) * Cout + o], base[(size_t)(n00 + WW + 1) * Cout + o]));
  outp[((size_t)b * MP + m) * Cout + o] = v;
}

// q [B][NPIX][64], kp [B][MP][64], vp [B][MP][256] -> attn [B][NPIX][256]
// grid (NPIX/32, B), block 256
__global__ __launch_bounds__(256) void attn_kernel(
    const float* __restrict__ q, const float* __restrict__ kp,
    const float* __restrict__ vp, float* __restrict__ attn)
{
  __shared__ float qs[32][68];
  __shared__ float ks[64][68];
  __shared__ float Ss[32][65];
  __shared__ float mrun_s[32], lrun_s[32], scale_s[32];
  const int n0 = blockIdx.x * 32;
  const int b  = blockIdx.y;
  const int t  = threadIdx.x;
  const float* qb  = q  + ((size_t)b * NPIX + n0) * CQK;
  const float* kpb = kp + (size_t)b * MP * CQK;
  const float* vpb = vp + (size_t)b * MP * CV;

  {
    const int nn = t >> 4;
    const int oo = (t & 15) << 2;
    *(float4*)&qs[nn][oo]      = *(const float4*)(qb + (size_t)nn * CQK + oo);
    *(float4*)&qs[nn + 16][oo] = *(const float4*)(qb + (size_t)(nn + 16) * CQK + oo);
  }
  if (t < 32) { mrun_s[t] = NEG_BIG; lrun_s[t] = 0.f; }

  const int sn = t & 31, smg = t >> 5;   // S-phase mapping
  const int nst = t >> 3, jst = t & 7;   // stats mapping
  const int nq = t & 7,  cq = t >> 3;    // attn-phase mapping
  float acc[4][8] = {};

  for (int m0 = 0; m0 < MP; m0 += 64) {
    #pragma unroll
    for (int k = 0; k < 4; ++k) {
      int row = (k << 4) + (t >> 4);
      int col = (t & 15) << 2;
      *(float4*)&ks[row][col] = *(const float4*)(kpb + (size_t)(m0 + row) * CQK + col);
    }
    __syncthreads();

    #pragma unroll
    for (int mmi = 0; mmi < 8; ++mmi) {
      const int mm = (smg << 3) + mmi;
      float s = 0.f;
      #pragma unroll
      for (int o4 = 0; o4 < 16; ++o4) {
        float4 qv = *(const float4*)&qs[sn][o4 << 2];
        float4 kv = *(const float4*)&ks[mm][o4 << 2];
        s += qv.x * kv.x + qv.y * kv.y + qv.z * kv.z + qv.w * kv.w;
      }
      Ss[sn][mm] = s;
    }
    __syncthreads();

    {
      float m_old = mrun_s[nst];
      float lmax = NEG_BIG;
      #pragma unroll
      for (int i = 0; i < 8; ++i) lmax = fmaxf(lmax, Ss[nst][(jst << 3) + i]);
      lmax = fmaxf(lmax, __shfl_xor(lmax, 1));
      lmax = fmaxf(lmax, __shfl_xor(lmax, 2));
      lmax = fmaxf(lmax, __shfl_xor(lmax, 4));
      float nmax = fmaxf(m_old, lmax);
      float lsum = 0.f;
      #pragma unroll
      for (int i = 0; i < 8; ++i) {
        float p = __expf(Ss[nst][(jst << 3) + i] - nmax);
        Ss[nst][(jst << 3) + i] = p;
        lsum += p;
      }
      lsum += __shfl_xor(lsum, 1);
      lsum += __shfl_xor(lsum, 2);
      lsum += __shfl_xor(lsum, 4);
      if (jst == 0) {
        float sc = __expf(m_old - nmax);
        scale_s[nst] = sc;
        lrun_s[nst] = lrun_s[nst] * sc + lsum;
        mrun_s[nst] = nmax;
      }
    }
    __syncthreads();

    #pragma unroll
    for (int i = 0; i < 4; ++i) {
      float sc = scale_s[(nq << 2) + i];
      #pragma unroll
      for (int j = 0; j < 8; ++j) acc[i][j] *= sc;
    }
    const float* vrow = vpb + (size_t)m0 * CV + (cq << 3);
    #pragma unroll 4
    for (int mm = 0; mm < 64; ++mm) {
      float4 v0 = *(const float4*)(vrow);
      float4 v1 = *(const float4*)(vrow + 4);
      float p0 = Ss[(nq << 2) + 0][mm];
      float p1 = Ss[(nq << 2) + 1][mm];
      float p2 = Ss[(nq << 2) + 2][mm];
      float p3 = Ss[(nq << 2) + 3][mm];
      acc[0][0] += p0 * v0.x; acc[0][1] += p0 * v0.y; acc[0][2] += p0 * v0.z; acc[0][3] += p0 * v0.w;
      acc[0][4] += p0 * v1.x; acc[0][5] += p0 * v1.y; acc[0][6] += p0 * v1.z; acc[0][7] += p0 * v1.w;
      acc[1][0] += p1 * v0.x; acc[1][1] += p1 * v0.y; acc[1][2] += p1 * v0.z; acc[1][3] += p1 * v0.w;
      acc[1][4] += p1 * v1.x; acc[1][5] += p1 * v1.y; acc[1][6] += p1 * v1.z; acc[1][7] += p1 * v1.w;
      acc[2][0] += p2 * v0.x; acc[2][1] += p2 * v0.y; acc[2][2] += p2 * v0.z; acc[2][3] += p2 * v0.w;
      acc[2][4] += p2 * v1.x; acc[2][5] += p2 * v1.y; acc[2][6] += p2 * v1.z; acc[2][7] += p2 * v1.w;
      acc[3][0] += p3 * v0.x; acc[3][1] += p3 * v0.y; acc[3][2] += p3 * v0.z; acc[3][3] += p3 * v0.w;
      acc[3][4] += p3 * v1.x; acc[3][5] += p3 * v1.y; acc[3][6] += p3 * v1.z; acc[3][7] += p3 * v1.w;
      vrow += CV;
    }
    __syncthreads();
  }

  float* ab = attn + ((size_t)b * NPIX + n0) * CV;
  #pragma unroll
  for (int i = 0; i < 4; ++i) {
    float inv = 1.0f / lrun_s[(nq << 2) + i];
    float4 r0 = make_float4(acc[i][0] * inv, acc[i][1] * inv, acc[i][2] * inv, acc[i][3] * inv);
    float4 r1 = make_float4(acc[i][4] * inv, acc[i][5] * inv, acc[i][6] * inv, acc[i][7] * inv);
    float* dst = ab + (size_t)((nq << 2) + i) * CV + (cq << 3);
    *(float4*)dst = r0;
    *(float4*)(dst + 4) = r1;
  }
}

// out[b][oc][n] = hidden + g*(sum_cv Wo[oc][cv]*attn[b][n][cv] + bo[oc])
// grid (NPIX/64, C_/64, B), block 256
__global__ __launch_bounds__(256) void out_kernel(
    const float* __restrict__ attn, const float* __restrict__ Wo,
    const float* __restrict__ bo, const float* __restrict__ hidden,
    const float* __restrict__ gating, float* __restrict__ outp)
{
  __shared__ float as_[32][68];  // [cv][n]
  __shared__ float ws_[32][68];  // [cv][oc]
  const int n0 = blockIdx.x * 64;
  const int o0 = blockIdx.y * 64;
  const int b  = blockIdx.z;
  const int t  = threadIdx.x;
  const int tn = t & 15, to = t >> 4;
  const float* ab = attn + (size_t)b * NPIX * CV;
  float acc[4][4] = {};
  for (int c0 = 0; c0 < CV; c0 += 32) {
    const int rr  = t >> 3;
    const int cc0 = (t & 7) << 2;
    float4 a0 = *(const float4*)(ab + (size_t)(n0 + rr) * CV + (c0 + cc0));
    float4 a1 = *(const float4*)(ab + (size_t)(n0 + rr + 32) * CV + (c0 + cc0));
    float4 w0 = *(const float4*)(Wo + (size_t)(o0 + rr) * CV + (c0 + cc0));
    float4 w1 = *(const float4*)(Wo + (size_t)(o0 + rr + 32) * CV + (c0 + cc0));
    as_[cc0 + 0][rr] = a0.x; as_[cc0 + 1][rr] = a0.y; as_[cc0 + 2][rr] = a0.z; as_[cc0 + 3][rr] = a0.w;
    as_[cc0 + 0][rr + 32] = a1.x; as_[cc0 + 1][rr + 32] = a1.y; as_[cc0 + 2][rr + 32] = a1.z; as_[cc0 + 3][rr + 32] = a1.w;
    ws_[cc0 + 0][rr] = w0.x; ws_[cc0 + 1][rr] = w0.y; ws_[cc0 + 2][rr] = w0.z; ws_[cc0 + 3][rr] = w0.w;
    ws_[cc0 + 0][rr + 32] = w1.x; ws_[cc0 + 1][rr + 32] = w1.y; ws_[cc0 + 2][rr + 32] = w1.z; ws_[cc0 + 3][rr + 32] = w1.w;
    __syncthreads();
    #pragma unroll
    for (int k = 0; k < 32; ++k) {
      float4 xv = *(const float4*)&as_[k][tn << 2];
      float4 wv = *(const float4*)&ws_[k][to << 2];
      acc[0][0] += wv.x * xv.x; acc[0][1] += wv.x * xv.y; acc[0][2] += wv.x * xv.z; acc[0][3] += wv.x * xv.w;
      acc[1][0] += wv.y * xv.x; acc[1][1] += wv.y * xv.y; acc[1][2] += wv.y * xv.z; acc[1][3] += wv.y * xv.w;
      acc[2][0] += wv.z * xv.x; acc[2][1] += wv.z * xv.y; acc[2][2] += wv.z * xv.z; acc[2][3] += wv.z * xv.w;
      acc[3][0] += wv.w * xv.x; acc[3][1] += wv.w * xv.y; acc[3][2] += wv.w * xv.z; acc[3][3] += wv.w * xv.w;
    }
    __syncthreads();
  }
  const float g = gating[0];
  const float* hb = hidden + ((size_t)b * C_ + o0) * NPIX + n0;
  float* ob = outp + ((size_t)b * C_ + o0) * NPIX + n0;
  #pragma unroll
  for (int oi = 0; oi < 4; ++oi) {
    const int oc = (to << 2) + oi;
    const float bov = bo[o0 + oc];
    float4 h = *(const float4*)(hb + (size_t)oc * NPIX + (tn << 2));
    float4 r;
    r.x = h.x + g * (acc[oi][0] + bov);
    r.y = h.y + g * (acc[oi][1] + bov);
    r.z = h.z + g * (acc[oi][2] + bov);
    r.w = h.w + g * (acc[oi][3] + bov);
    *(float4*)(ob + (size_t)oc * NPIX + (tn << 2)) = r;
  }
}

extern "C" void kernel_launch(void* const* d_in, const int* in_sizes, int n_in,
                              void* d_out, int out_size, void* d_ws, size_t ws_size,
                              hipStream_t stream)
{
  const float* hidden = (const float*)d_in[0];
  const float* Wq = (const float*)d_in[1];
  const float* Wk = (const float*)d_in[2];
  const float* Wv = (const float*)d_in[3];
  const float* Wo = (const float*)d_in[4];
  const float* bo = (const float*)d_in[5];
  const float* gating = (const float*)d_in[6];
  float* out = (float*)d_out;
  float* ws = (float*)d_ws;

  // ws layout (floats):
  //   q      [B][N][64]   @ 0          (4,194,304)
  //   kfull  [B][N][64]   @ 4,194,304  (4,194,304)
  //   vfull  [B][N][256]  @ 8,388,608  (16,777,216)
  //   kp     [B][M][64]   @ 25,165,824 (1,048,576)
  //   vp     [B][M][256]  @ 26,214,400 (4,194,304)
  //   attn   [B][N][256]  @ 4,194,304  (aliases dead kfull/vfull)
  // peak = 30,408,704 floats = ~116 MiB of d_ws
  float* q  = ws;
  float* kf = ws + 4194304;
  float* vf = ws + 8388608;
  float* kp = ws + 25165824;
  float* vp = ws + 26214400;
  float* at = ws + 4194304;

  proj_kernel<<<dim3(NPIX / 64, 1, B_), 256, 0, stream>>>(hidden, Wq, q, CQK);
  proj_kernel<<<dim3(NPIX / 64, 1, B_), 256, 0, stream>>>(hidden, Wk, kf, CQK);
  proj_kernel<<<dim3(NPIX / 64, 4, B_), 256, 0, stream>>>(hidden, Wv, vf, CV);
  pool_kernel<<<dim3((B_ * MP * CQK) / 256), 256, 0, stream>>>(kf, kp, CQK);
  pool_kernel<<<dim3((B_ * MP * CV) / 256), 256, 0, stream>>>(vf, vp, CV);
  attn_kernel<<<dim3(NPIX / 32, B_), 256, 0, stream>>>(q, kp, vp, at);
  out_kernel<<<dim3(NPIX / 64, C_ / 64, B_), 256, 0, stream>>>(at, Wo, bo, hidden, gating, out);
}

// Round 4
// 1019.427 us; speedup vs baseline: 1.8083x; 1.8083x over previous
//
#include <hip/hip_runtime.h>
#include <math.h>

#define B_ 16
#define C_ 512
#define NPIX 4096
#define WW 64
#define CQK 64
#define CV 256
#define MP 1024
#define NEG_BIG (-1e30f)

typedef __attribute__((ext_vector_type(8))) short short8;
typedef __attribute__((ext_vector_type(4))) float f32x4;

static __device__ __forceinline__ unsigned short f2bf(float f) {
  unsigned int u = __float_as_uint(f);
  unsigned int r = u + 0x7FFFu + ((u >> 16) & 1u);
  return (unsigned short)(r >> 16);
}
static __device__ __forceinline__ float bf2f(unsigned short h) {
  return __uint_as_float(((unsigned int)h) << 16);
}

// ---------------- fp32 projection (unchanged, known-good) ----------------
// out[b][n][o] = sum_c W[o][c] * x[b][c][n];  grid (NPIX/64, Cout/64, B)
__global__ __launch_bounds__(256) void proj_kernel(
    const float* __restrict__ x, const float* __restrict__ W,
    float* __restrict__ outp, int Cout)
{
  __shared__ float xs[32][68];
  __shared__ float wsh[32][68];
  const int n0 = blockIdx.x * 64;
  const int o0 = blockIdx.y * 64;
  const int b  = blockIdx.z;
  const int t  = threadIdx.x;
  const int tn = t & 15, to = t >> 4;
  const float* xb = x + (size_t)b * C_ * NPIX;
  float acc[4][4] = {};
  for (int c0 = 0; c0 < C_; c0 += 32) {
    const int cc = t >> 4;
    const int nn = (t & 15) << 2;
    float4 v0 = *(const float4*)(xb + (size_t)(c0 + cc) * NPIX + (n0 + nn));
    float4 v1 = *(const float4*)(xb + (size_t)(c0 + cc + 16) * NPIX + (n0 + nn));
    const int oo  = t >> 3;
    const int cc0 = (t & 7) << 2;
    float4 w0 = *(const float4*)(W + (size_t)(o0 + oo) * C_ + (c0 + cc0));
    float4 w1 = *(const float4*)(W + (size_t)(o0 + oo + 32) * C_ + (c0 + cc0));
    *(float4*)&xs[cc][nn] = v0;
    *(float4*)&xs[cc + 16][nn] = v1;
    wsh[cc0 + 0][oo] = w0.x; wsh[cc0 + 1][oo] = w0.y;
    wsh[cc0 + 2][oo] = w0.z; wsh[cc0 + 3][oo] = w0.w;
    wsh[cc0 + 0][oo + 32] = w1.x; wsh[cc0 + 1][oo + 32] = w1.y;
    wsh[cc0 + 2][oo + 32] = w1.z; wsh[cc0 + 3][oo + 32] = w1.w;
    __syncthreads();
    #pragma unroll
    for (int k = 0; k < 32; ++k) {
      float4 xv = *(const float4*)&xs[k][tn << 2];
      float4 wv = *(const float4*)&wsh[k][to << 2];
      acc[0][0] += wv.x * xv.x; acc[0][1] += wv.x * xv.y; acc[0][2] += wv.x * xv.z; acc[0][3] += wv.x * xv.w;
      acc[1][0] += wv.y * xv.x; acc[1][1] += wv.y * xv.y; acc[1][2] += wv.y * xv.z; acc[1][3] += wv.y * xv.w;
      acc[2][0] += wv.z * xv.x; acc[2][1] += wv.z * xv.y; acc[2][2] += wv.z * xv.z; acc[2][3] += wv.z * xv.w;
      acc[3][0] += wv.w * xv.x; acc[3][1] += wv.w * xv.y; acc[3][2] += wv.w * xv.z; acc[3][3] += wv.w * xv.w;
    }
    __syncthreads();
  }
  float* ob = outp + ((size_t)b * NPIX + n0) * Cout + o0;
  #pragma unroll
  for (int ni = 0; ni < 4; ++ni) {
    float4 r = make_float4(acc[0][ni], acc[1][ni], acc[2][ni], acc[3][ni]);
    *(float4*)(ob + (size_t)((tn << 2) + ni) * Cout + (to << 2)) = r;
  }
}

// ---------------- K pool + hi/lo bf16 split ----------------
// kf [B][N][64] -> kphi/kplo [B][MP][64] bf16
__global__ __launch_bounds__(256) void pool_k_kernel(
    const float* __restrict__ kf, unsigned short* __restrict__ kphi,
    unsigned short* __restrict__ kplo)
{
  int id = blockIdx.x * 256 + threadIdx.x;   // B*MP*64 = 1,048,576
  int ch = id & 63;
  int m  = (id >> 6) & (MP - 1);
  int b  = id >> 16;
  int mi = m >> 5, mj = m & 31;
  int n00 = mi * 128 + mj * 2;
  const float* base = kf + ((size_t)b * NPIX + n00) * 64 + ch;
  float v = fmaxf(fmaxf(base[0], base[64]),
                  fmaxf(base[64 * 64], base[65 * 64]));
  unsigned short h = f2bf(v);
  kphi[id] = h;
  kplo[id] = f2bf(v - bf2f(h));
}

// ---------------- V pool + transpose to bf16 ----------------
// vf [B][N][256] -> vt [B][256][MP] bf16;  grid (MP/64, CV/64, B)
__global__ __launch_bounds__(256) void pool_vt_kernel(
    const float* __restrict__ vf, unsigned short* __restrict__ vt)
{
  __shared__ float lds_t[64][65];
  const int m0  = blockIdx.x * 64;
  const int cv0 = blockIdx.y * 64;
  const int b   = blockIdx.z;
  const int t   = threadIdx.x;
  const int lane = t & 63;
  const int mw   = t >> 6;      // 4 m-workers
  #pragma unroll
  for (int it = 0; it < 16; ++it) {
    int m_loc = it * 4 + mw;
    int m = m0 + m_loc;
    int mi = m >> 5, mj = m & 31;
    int n00 = mi * 128 + mj * 2;
    const float* p = vf + ((size_t)b * NPIX + n00) * CV + cv0 + lane;
    float v = fmaxf(fmaxf(p[0], p[CV]),
                    fmaxf(p[64 * CV], p[65 * CV]));
    lds_t[m_loc][lane] = v;
  }
  __syncthreads();
  const int cv_loc = t >> 2;
  const int mg = t & 3;
  unsigned short tmp[16];
  #pragma unroll
  for (int i = 0; i < 16; ++i) tmp[i] = f2bf(lds_t[mg * 16 + i][cv_loc]);
  unsigned short* dst = vt + ((size_t)b * CV + cv0 + cv_loc) * MP + m0 + mg * 16;
  short8 o0_, o1_;
  #pragma unroll
  for (int j = 0; j < 8; ++j) { o0_[j] = (short)tmp[j]; o1_[j] = (short)tmp[8 + j]; }
  *(short8*)dst = o0_;
  *(short8*)(dst + 8) = o1_;
}

// ---------------- Wo -> bf16 ----------------
__global__ __launch_bounds__(256) void wof16_kernel(
    const float* __restrict__ Wo, unsigned short* __restrict__ wobf)
{
  int id = blockIdx.x * 256 + threadIdx.x;  // 131072
  wobf[id] = f2bf(Wo[id]);
}

// ---------------- MFMA flash attention ----------------
// q [B][N][64] f32; kphi/kplo [B][MP][64] bf16; vt [B][256][MP] bf16
// -> at [B][N][256] bf16.  grid (NPIX/64, B), 256 thr (4 waves, 16 q-rows each)
__global__ __launch_bounds__(256) void attn_mfma_kernel(
    const float* __restrict__ q, const unsigned short* __restrict__ kphi,
    const unsigned short* __restrict__ kplo, const unsigned short* __restrict__ vt,
    unsigned short* __restrict__ at)
{
  __shared__ float plds[4][16][65];
  const int n0 = blockIdx.x * 64;
  const int b  = blockIdx.y;
  const int t  = threadIdx.x;
  const int w    = t >> 6;
  const int lane = t & 63;
  const int c = lane & 15;
  const int g = lane >> 4;

  // Q fragments, split hi/lo (resident for whole kernel)
  short8 qhi[2], qlo[2];
  {
    const float* qrow = q + ((size_t)b * NPIX + n0 + w * 16 + c) * 64;
    #pragma unroll
    for (int ks = 0; ks < 2; ++ks) {
      float v[8];
      *(float4*)&v[0] = *(const float4*)(qrow + ks * 32 + g * 8);
      *(float4*)&v[4] = *(const float4*)(qrow + ks * 32 + g * 8 + 4);
      short8 hi, lo;
      #pragma unroll
      for (int j = 0; j < 8; ++j) {
        unsigned short h = f2bf(v[j]);
        hi[j] = (short)h;
        lo[j] = (short)f2bf(v[j] - bf2f(h));
      }
      qhi[ks] = hi; qlo[ks] = lo;
    }
  }

  f32x4 acc[16];
  #pragma unroll
  for (int i = 0; i < 16; ++i) { acc[i][0] = 0.f; acc[i][1] = 0.f; acc[i][2] = 0.f; acc[i][3] = 0.f; }
  float mrun[4] = {NEG_BIG, NEG_BIG, NEG_BIG, NEG_BIG};
  float lrun[4] = {0.f, 0.f, 0.f, 0.f};

  const unsigned short* khb = kphi + (size_t)b * MP * 64;
  const unsigned short* klb = kplo + (size_t)b * MP * 64;
  const unsigned short* vtb = vt + (size_t)b * CV * MP;

  for (int m0 = 0; m0 < MP; m0 += 64) {
    // ---- QK^T: S[16 q][64 m], split bf16 (hi*hi + lo*hi + hi*lo) ----
    f32x4 s[4];
    #pragma unroll
    for (int mt = 0; mt < 4; ++mt) { s[mt][0]=0.f; s[mt][1]=0.f; s[mt][2]=0.f; s[mt][3]=0.f; }
    #pragma unroll
    for (int mt = 0; mt < 4; ++mt) {
      const size_t krow = (size_t)(m0 + mt * 16 + c) * 64;
      #pragma unroll
      for (int ks = 0; ks < 2; ++ks) {
        short8 kh = *(const short8*)(khb + krow + ks * 32 + g * 8);
        short8 kl = *(const short8*)(klb + krow + ks * 32 + g * 8);
        s[mt] = __builtin_amdgcn_mfma_f32_16x16x32_bf16(qhi[ks], kh, s[mt], 0, 0, 0);
        s[mt] = __builtin_amdgcn_mfma_f32_16x16x32_bf16(qlo[ks], kh, s[mt], 0, 0, 0);
        s[mt] = __builtin_amdgcn_mfma_f32_16x16x32_bf16(qhi[ks], kl, s[mt], 0, 0, 0);
      }
    }
    // ---- online softmax (rows live on (g,r); reduce over 16 c-lanes) ----
    float scal[4];
    #pragma unroll
    for (int r = 0; r < 4; ++r) {
      float tm = fmaxf(fmaxf(s[0][r], s[1][r]), fmaxf(s[2][r], s[3][r]));
      tm = fmaxf(tm, __shfl_xor(tm, 1));
      tm = fmaxf(tm, __shfl_xor(tm, 2));
      tm = fmaxf(tm, __shfl_xor(tm, 4));
      tm = fmaxf(tm, __shfl_xor(tm, 8));
      float nm = fmaxf(mrun[r], tm);
      float sc = __expf(mrun[r] - nm);
      float p0 = __expf(s[0][r] - nm);
      float p1 = __expf(s[1][r] - nm);
      float p2 = __expf(s[2][r] - nm);
      float p3 = __expf(s[3][r] - nm);
      s[0][r] = p0; s[1][r] = p1; s[2][r] = p2; s[3][r] = p3;
      float rs = (p0 + p1) + (p2 + p3);
      rs += __shfl_xor(rs, 1);
      rs += __shfl_xor(rs, 2);
      rs += __shfl_xor(rs, 4);
      rs += __shfl_xor(rs, 8);
      lrun[r] = lrun[r] * sc + rs;
      mrun[r] = nm;
      scal[r] = sc;
    }
    // rescale PV accumulator (same lane mapping: row = 4g+r)
    #pragma unroll
    for (int cvt = 0; cvt < 16; ++cvt) {
      #pragma unroll
      for (int r = 0; r < 4; ++r) acc[cvt][r] *= scal[r];
    }
    // ---- P: C-layout -> A-layout via per-wave LDS round-trip ----
    #pragma unroll
    for (int mt = 0; mt < 4; ++mt) {
      #pragma unroll
      for (int r = 0; r < 4; ++r)
        plds[w][4 * g + r][mt * 16 + c] = s[mt][r];
    }
    short8 pf[2];
    #pragma unroll
    for (int ks = 0; ks < 2; ++ks) {
      float pv[8];
      *(float4*)&pv[0] = *(const float4*)&plds[w][c][ks * 32 + g * 8];
      *(float4*)&pv[4] = *(const float4*)&plds[w][c][ks * 32 + g * 8 + 4];
      short8 f;
      #pragma unroll
      for (int j = 0; j < 8; ++j) f[j] = (short)f2bf(pv[j]);
      pf[ks] = f;
    }
    // ---- PV: attn[16 q][256 cv] += P * V ----
    #pragma unroll
    for (int cvt = 0; cvt < 16; ++cvt) {
      const unsigned short* vrow = vtb + (size_t)(cvt * 16 + c) * MP + m0 + g * 8;
      short8 v0 = *(const short8*)(vrow);
      short8 v1 = *(const short8*)(vrow + 32);
      acc[cvt] = __builtin_amdgcn_mfma_f32_16x16x32_bf16(pf[0], v0, acc[cvt], 0, 0, 0);
      acc[cvt] = __builtin_amdgcn_mfma_f32_16x16x32_bf16(pf[1], v1, acc[cvt], 0, 0, 0);
    }
  }
  // ---- epilogue: normalize, write at[b][n][cv] bf16 ----
  unsigned short* ab = at + ((size_t)b * NPIX + n0 + w * 16) * CV;
  #pragma unroll
  for (int r = 0; r < 4; ++r) {
    float inv = 1.0f / lrun[r];
    int row = 4 * g + r;
    #pragma unroll
    for (int cvt = 0; cvt < 16; ++cvt)
      ab[(size_t)row * CV + cvt * 16 + c] = f2bf(acc[cvt][r] * inv);
  }
}

// ---------------- MFMA output projection + bias + gating + residual ----------------
// out[b][oc][n] = hidden + g*(sum_cv Wo[oc][cv]*at[n][cv] + bo[oc])
// grid (NPIX/64, C_/64, B), 256 thr (4 waves; wave = 16 oc x 64 n)
__global__ __launch_bounds__(256) void out_mfma_kernel(
    const unsigned short* __restrict__ at, const unsigned short* __restrict__ wobf,
    const float* __restrict__ bo, const float* __restrict__ hidden,
    const float* __restrict__ gating, float* __restrict__ outp)
{
  const int n0 = blockIdx.x * 64;
  const int o0 = blockIdx.y * 64;
  const int b  = blockIdx.z;
  const int t  = threadIdx.x;
  const int w    = t >> 6;
  const int lane = t & 63;
  const int c = lane & 15;
  const int g = lane >> 4;
  f32x4 acc[4];
  #pragma unroll
  for (int i = 0; i < 4; ++i) { acc[i][0]=0.f; acc[i][1]=0.f; acc[i][2]=0.f; acc[i][3]=0.f; }
  const unsigned short* ab = at + (size_t)b * NPIX * CV;
  #pragma unroll
  for (int ks = 0; ks < 8; ++ks) {
    short8 aw = *(const short8*)(wobf + (size_t)(o0 + w * 16 + c) * CV + ks * 32 + g * 8);
    #pragma unroll
    for (int nt = 0; nt < 4; ++nt) {
      short8 bv = *(const short8*)(ab + (size_t)(n0 + nt * 16 + c) * CV + ks * 32 + g * 8);
      acc[nt] = __builtin_amdgcn_mfma_f32_16x16x32_bf16(aw, bv, acc[nt], 0, 0, 0);
    }
  }
  const float gt = gating[0];
  #pragma unroll
  for (int nt = 0; nt < 4; ++nt) {
    #pragma unroll
    for (int r = 0; r < 4; ++r) {
      int oc = o0 + w * 16 + 4 * g + r;
      int n  = n0 + nt * 16 + c;
      size_t idx = ((size_t)b * C_ + oc) * NPIX + n;
      outp[idx] = hidden[idx] + gt * (acc[nt][r] + bo[oc]);
    }
  }
}

extern "C" void kernel_launch(void* const* d_in, const int* in_sizes, int n_in,
                              void* d_out, int out_size, void* d_ws, size_t ws_size,
                              hipStream_t stream)
{
  const float* hidden = (const float*)d_in[0];
  const float* Wq = (const float*)d_in[1];
  const float* Wk = (const float*)d_in[2];
  const float* Wv = (const float*)d_in[3];
  const float* Wo = (const float*)d_in[4];
  const float* bo = (const float*)d_in[5];
  const float* gating = (const float*)d_in[6];
  float* out = (float*)d_out;
  char* ws = (char*)d_ws;

  // ws layout (bytes):
  //   q    f32 [B][N][64]    @ 0        (16 MB)
  //   kf   f32 [B][N][64]    @ 16 MB    (16 MB)
  //   vf   f32 [B][N][256]   @ 32 MB    (64 MB)   } at bf16 [B][N][256] (32 MB)
  //   at   bf16               @ 32 MB   (aliases vf; vf dead after pool_vt)
  //   kphi bf16 [B][MP][64]  @ 96 MB    (2 MB)
  //   kplo bf16 [B][MP][64]  @ 98 MB    (2 MB)
  //   vt   bf16 [B][256][MP] @ 100 MB   (8 MB)
  //   wobf bf16 [512][256]   @ 108 MB   (256 KB)
  float* q  = (float*)(ws);
  float* kf = (float*)(ws + (16u << 20));
  float* vf = (float*)(ws + (32u << 20));
  unsigned short* at   = (unsigned short*)(ws + (32u << 20));
  unsigned short* kphi = (unsigned short*)(ws + (96u << 20));
  unsigned short* kplo = (unsigned short*)(ws + (98u << 20));
  unsigned short* vt   = (unsigned short*)(ws + (100u << 20));
  unsigned short* wobf = (unsigned short*)(ws + (108u << 20));

  proj_kernel<<<dim3(NPIX / 64, 1, B_), 256, 0, stream>>>(hidden, Wq, q, CQK);
  proj_kernel<<<dim3(NPIX / 64, 1, B_), 256, 0, stream>>>(hidden, Wk, kf, CQK);
  proj_kernel<<<dim3(NPIX / 64, 4, B_), 256, 0, stream>>>(hidden, Wv, vf, CV);
  pool_k_kernel<<<dim3((B_ * MP * CQK) / 256), 256, 0, stream>>>(kf, kphi, kplo);
  pool_vt_kernel<<<dim3(MP / 64, CV / 64, B_), 256, 0, stream>>>(vf, vt);
  wof16_kernel<<<dim3((C_ * CV) / 256), 256, 0, stream>>>(Wo, wobf);
  attn_mfma_kernel<<<dim3(NPIX / 64, B_), 256, 0, stream>>>(q, kphi, kplo, vt, at);
  out_mfma_kernel<<<dim3(NPIX / 64, C_ / 64, B_), 256, 0, stream>>>(at, wobf, bo, hidden, gating, out);
}

// Round 8
// 808.297 us; speedup vs baseline: 2.2806x; 1.2612x over previous
//
#include <hip/hip_runtime.h>
#include <math.h>

#define B_ 16
#define C_ 512
#define NPIX 4096
#define WW 64
#define CQK 64
#define CV 256
#define MP 1024
#define NEG_BIG (-1e30f)

typedef __attribute__((ext_vector_type(8))) short short8;
typedef __attribute__((ext_vector_type(4))) float f32x4;

static __device__ __forceinline__ unsigned short f2bf(float f) {
  unsigned int u = __float_as_uint(f);
  unsigned int r = u + 0x7FFFu + ((u >> 16) & 1u);
  return (unsigned short)(r >> 16);
}
static __device__ __forceinline__ float bf2f(unsigned short h) {
  return __uint_as_float(((unsigned int)h) << 16);
}

// ---------------- weight split (f32 -> bf16 hi [+ lo]) ----------------
__global__ __launch_bounds__(256) void split_w_kernel(
    const float* __restrict__ src, unsigned short* __restrict__ hi,
    unsigned short* __restrict__ lo, int n)
{
  int i = blockIdx.x * 256 + threadIdx.x;
  if (i >= n) return;
  float f = src[i];
  unsigned short h = f2bf(f);
  hi[i] = h;
  if (lo) lo[i] = f2bf(f - bf2f(h));
}

// ---------------- fused q/k/v projection (bf16 MFMA) ----------------
// x [b][c][n] f32 -> qhi/qlo/khi/klo [b][n][64] bf16, v [b][n][256] bf16
// q,k: split-bf16 (3 MFMA) for fp32-grade scores; v: single bf16.
// grid (NPIX/64, B), block 256 (4 waves).
// Wave w: q-ch [16w,16w+16), k-ch [16w,16w+16), v-ch [64w,64w+64), all 64 n.
__global__ __launch_bounds__(256) void qkv_kernel(
    const float* __restrict__ x,
    const unsigned short* __restrict__ wqhi, const unsigned short* __restrict__ wqlo,
    const unsigned short* __restrict__ wkhi, const unsigned short* __restrict__ wklo,
    const unsigned short* __restrict__ wvhi,
    unsigned short* __restrict__ qhi, unsigned short* __restrict__ qlo,
    unsigned short* __restrict__ khi, unsigned short* __restrict__ klo,
    unsigned short* __restrict__ vout)
{
  __shared__ float xs[64][36];   // [n_loc][c_loc], pad 36: writes 2-way, b128 reads at floor
  const int n0 = blockIdx.x * 64;
  const int b  = blockIdx.y;
  const int t  = threadIdx.x;
  const int w    = t >> 6;
  const int lane = t & 63;
  const int c = lane & 15;
  const int g = lane >> 4;
  const float* xb = x + (size_t)b * C_ * NPIX + n0;

  f32x4 aq[4], ak[4], av[4][4];
  #pragma unroll
  for (int nt = 0; nt < 4; ++nt) {
    aq[nt][0]=0.f; aq[nt][1]=0.f; aq[nt][2]=0.f; aq[nt][3]=0.f;
    ak[nt][0]=0.f; ak[nt][1]=0.f; ak[nt][2]=0.f; ak[nt][3]=0.f;
    #pragma unroll
    for (int ot = 0; ot < 4; ++ot) {
      av[ot][nt][0]=0.f; av[ot][nt][1]=0.f; av[ot][nt][2]=0.f; av[ot][nt][3]=0.f;
    }
  }

  const int cc = lane & 31;                 // staging: channel row
  const int nb = w * 16 + ((lane >> 5) << 3);  // staging: n base (8 n's)

  for (int c0 = 0; c0 < C_; c0 += 32) {
    const float* srcp = xb + (size_t)(c0 + cc) * NPIX + nb;
    float4 u0 = *(const float4*)(srcp);
    float4 u1 = *(const float4*)(srcp + 4);
    __syncthreads();
    xs[nb + 0][cc] = u0.x; xs[nb + 1][cc] = u0.y; xs[nb + 2][cc] = u0.z; xs[nb + 3][cc] = u0.w;
    xs[nb + 4][cc] = u1.x; xs[nb + 5][cc] = u1.y; xs[nb + 6][cc] = u1.z; xs[nb + 7][cc] = u1.w;
    __syncthreads();

    // A-fragments: rows n, k-elems c (split hi/lo)
    short8 xhi[4], xlo[4];
    #pragma unroll
    for (int nt = 0; nt < 4; ++nt) {
      float f[8];
      *(float4*)&f[0] = *(const float4*)&xs[nt * 16 + c][g * 8];
      *(float4*)&f[4] = *(const float4*)&xs[nt * 16 + c][g * 8 + 4];
      short8 hi, lo;
      #pragma unroll
      for (int j = 0; j < 8; ++j) {
        unsigned short h = f2bf(f[j]);
        hi[j] = (short)h;
        lo[j] = (short)f2bf(f[j] - bf2f(h));
      }
      xhi[nt] = hi; xlo[nt] = lo;
    }
    // B-fragments: weight rows (o), k-elems c
    const size_t wrow = (size_t)(w * 16 + c) * C_ + c0 + g * 8;
    short8 bqh = *(const short8*)(wqhi + wrow);
    short8 bql = *(const short8*)(wqlo + wrow);
    short8 bkh = *(const short8*)(wkhi + wrow);
    short8 bkl = *(const short8*)(wklo + wrow);
    #pragma unroll
    for (int nt = 0; nt < 4; ++nt) {
      aq[nt] = __builtin_amdgcn_mfma_f32_16x16x32_bf16(xhi[nt], bqh, aq[nt], 0, 0, 0);
      aq[nt] = __builtin_amdgcn_mfma_f32_16x16x32_bf16(xlo[nt], bqh, aq[nt], 0, 0, 0);
      aq[nt] = __builtin_amdgcn_mfma_f32_16x16x32_bf16(xhi[nt], bql, aq[nt], 0, 0, 0);
      ak[nt] = __builtin_amdgcn_mfma_f32_16x16x32_bf16(xhi[nt], bkh, ak[nt], 0, 0, 0);
      ak[nt] = __builtin_amdgcn_mfma_f32_16x16x32_bf16(xlo[nt], bkh, ak[nt], 0, 0, 0);
      ak[nt] = __builtin_amdgcn_mfma_f32_16x16x32_bf16(xhi[nt], bkl, ak[nt], 0, 0, 0);
    }
    #pragma unroll
    for (int ot = 0; ot < 4; ++ot) {
      short8 bv = *(const short8*)(wvhi + (size_t)(w * 64 + ot * 16 + c) * C_ + c0 + g * 8);
      #pragma unroll
      for (int nt = 0; nt < 4; ++nt)
        av[ot][nt] = __builtin_amdgcn_mfma_f32_16x16x32_bf16(xhi[nt], bv, av[ot][nt], 0, 0, 0);
    }
  }

  // epilogue: D[row=4g+r -> n][col=c -> o]
  #pragma unroll
  for (int nt = 0; nt < 4; ++nt) {
    #pragma unroll
    for (int r = 0; r < 4; ++r) {
      int n = n0 + nt * 16 + 4 * g + r;
      size_t qi = ((size_t)b * NPIX + n) * 64 + w * 16 + c;
      float fq = aq[nt][r];
      unsigned short hq = f2bf(fq);
      qhi[qi] = hq; qlo[qi] = f2bf(fq - bf2f(hq));
      float fk = ak[nt][r];
      unsigned short hk = f2bf(fk);
      khi[qi] = hk; klo[qi] = f2bf(fk - bf2f(hk));
      size_t vi = ((size_t)b * NPIX + n) * CV + w * 64;
      #pragma unroll
      for (int ot = 0; ot < 4; ++ot)
        vout[vi + ot * 16 + c] = f2bf(av[ot][nt][r]);
    }
  }
}

// ---------------- K pool (bf16 hi/lo in -> pooled hi/lo out) ----------------
__global__ __launch_bounds__(256) void pool_k_kernel(
    const unsigned short* __restrict__ khi, const unsigned short* __restrict__ klo,
    unsigned short* __restrict__ kphi, unsigned short* __restrict__ kplo)
{
  int id = blockIdx.x * 256 + threadIdx.x;   // B*MP*64 = 1,048,576
  int ch = id & 63;
  int m  = (id >> 6) & (MP - 1);
  int b  = id >> 16;
  int mi = m >> 5, mj = m & 31;
  int n00 = mi * 128 + mj * 2;
  size_t base = ((size_t)b * NPIX + n00) * 64 + ch;
  float v0 = bf2f(khi[base])            + bf2f(klo[base]);
  float v1 = bf2f(khi[base + 64])       + bf2f(klo[base + 64]);
  float v2 = bf2f(khi[base + 64 * 64])  + bf2f(klo[base + 64 * 64]);
  float v3 = bf2f(khi[base + 65 * 64])  + bf2f(klo[base + 65 * 64]);
  float v = fmaxf(fmaxf(v0, v1), fmaxf(v2, v3));
  unsigned short h = f2bf(v);
  kphi[id] = h;
  kplo[id] = f2bf(v - bf2f(h));
}

// ---------------- V pool + transpose (bf16 in -> vt bf16) ----------------
// v [B][NPIX][256] bf16 -> vt [B][256][MP] bf16;  grid (MP/64, CV/64, B)
__global__ __launch_bounds__(256) void pool_vt_kernel(
    const unsigned short* __restrict__ v, unsigned short* __restrict__ vt)
{
  __shared__ float lds_t[64][65];
  const int m0  = blockIdx.x * 64;
  const int cv0 = blockIdx.y * 64;
  const int b   = blockIdx.z;
  const int t   = threadIdx.x;
  const int lane = t & 63;
  const int mw   = t >> 6;
  #pragma unroll
  for (int it = 0; it < 16; ++it) {
    int m_loc = it * 4 + mw;
    int m = m0 + m_loc;
    int mi = m >> 5, mj = m & 31;
    int n00 = mi * 128 + mj * 2;
    const unsigned short* p = v + ((size_t)b * NPIX + n00) * CV + cv0 + lane;
    float x0 = bf2f(p[0]), x1 = bf2f(p[CV]);
    float x2 = bf2f(p[64 * CV]), x3 = bf2f(p[65 * CV]);
    lds_t[m_loc][lane] = fmaxf(fmaxf(x0, x1), fmaxf(x2, x3));
  }
  __syncthreads();
  const int cv_loc = t >> 2;
  const int mg = t & 3;
  unsigned short tmp[16];
  #pragma unroll
  for (int i = 0; i < 16; ++i) tmp[i] = f2bf(lds_t[mg * 16 + i][cv_loc]);
  unsigned short* dst = vt + ((size_t)b * CV + cv0 + cv_loc) * MP + m0 + mg * 16;
  short8 o0_, o1_;
  #pragma unroll
  for (int j = 0; j < 8; ++j) { o0_[j] = (short)tmp[j]; o1_[j] = (short)tmp[8 + j]; }
  *(short8*)dst = o0_;
  *(short8*)(dst + 8) = o1_;
}

// ---------------- MFMA flash attention ----------------
// qhi/qlo [B][N][64] bf16; kphi/kplo [B][MP][64] bf16; vt [B][256][MP] bf16
// -> at [B][N][256] bf16.  grid (NPIX/64, B), 256 thr (4 waves, 16 q-rows each)
__global__ __launch_bounds__(256) void attn_mfma_kernel(
    const unsigned short* __restrict__ qhi, const unsigned short* __restrict__ qlo,
    const unsigned short* __restrict__ kphi, const unsigned short* __restrict__ kplo,
    const unsigned short* __restrict__ vt, unsigned short* __restrict__ at)
{
  __shared__ float plds[4][16][65];
  const int n0 = blockIdx.x * 64;
  const int b  = blockIdx.y;
  const int t  = threadIdx.x;
  const int w    = t >> 6;
  const int lane = t & 63;
  const int c = lane & 15;
  const int g = lane >> 4;

  // Q fragments (pre-split bf16)
  short8 qh[2], ql[2];
  {
    const unsigned short* qhr = qhi + ((size_t)b * NPIX + n0 + w * 16 + c) * 64;
    const unsigned short* qlr = qlo + ((size_t)b * NPIX + n0 + w * 16 + c) * 64;
    #pragma unroll
    for (int ks = 0; ks < 2; ++ks) {
      qh[ks] = *(const short8*)(qhr + ks * 32 + g * 8);
      ql[ks] = *(const short8*)(qlr + ks * 32 + g * 8);
    }
  }

  f32x4 acc[16];
  #pragma unroll
  for (int i = 0; i < 16; ++i) { acc[i][0]=0.f; acc[i][1]=0.f; acc[i][2]=0.f; acc[i][3]=0.f; }
  float mrun[4] = {NEG_BIG, NEG_BIG, NEG_BIG, NEG_BIG};
  float lrun[4] = {0.f, 0.f, 0.f, 0.f};

  const unsigned short* khb = kphi + (size_t)b * MP * 64;
  const unsigned short* klb = kplo + (size_t)b * MP * 64;
  const unsigned short* vtb = vt + (size_t)b * CV * MP;

  for (int m0 = 0; m0 < MP; m0 += 64) {
    // ---- QK^T (split bf16) ----
    f32x4 s[4];
    #pragma unroll
    for (int mt = 0; mt < 4; ++mt) { s[mt][0]=0.f; s[mt][1]=0.f; s[mt][2]=0.f; s[mt][3]=0.f; }
    #pragma unroll
    for (int mt = 0; mt < 4; ++mt) {
      const size_t krow = (size_t)(m0 + mt * 16 + c) * 64;
      #pragma unroll
      for (int ks = 0; ks < 2; ++ks) {
        short8 kh = *(const short8*)(khb + krow + ks * 32 + g * 8);
        short8 kl = *(const short8*)(klb + krow + ks * 32 + g * 8);
        s[mt] = __builtin_amdgcn_mfma_f32_16x16x32_bf16(qh[ks], kh, s[mt], 0, 0, 0);
        s[mt] = __builtin_amdgcn_mfma_f32_16x16x32_bf16(ql[ks], kh, s[mt], 0, 0, 0);
        s[mt] = __builtin_amdgcn_mfma_f32_16x16x32_bf16(qh[ks], kl, s[mt], 0, 0, 0);
      }
    }
    // ---- online softmax with defer-max (THR=8) ----
    float tmax[4];
    #pragma unroll
    for (int r = 0; r < 4; ++r) {
      float tm = fmaxf(fmaxf(s[0][r], s[1][r]), fmaxf(s[2][r], s[3][r]));
      tm = fmaxf(tm, __shfl_xor(tm, 1));
      tm = fmaxf(tm, __shfl_xor(tm, 2));
      tm = fmaxf(tm, __shfl_xor(tm, 4));
      tm = fmaxf(tm, __shfl_xor(tm, 8));
      tmax[r] = tm;
    }
    float growth = fmaxf(fmaxf(tmax[0] - mrun[0], tmax[1] - mrun[1]),
                         fmaxf(tmax[2] - mrun[2], tmax[3] - mrun[3]));
    if (!__all(growth <= 8.0f)) {
      float scal[4];
      #pragma unroll
      for (int r = 0; r < 4; ++r) {
        float nm = fmaxf(mrun[r], tmax[r]);
        float sc = __expf(mrun[r] - nm);
        lrun[r] *= sc;
        mrun[r] = nm;
        scal[r] = sc;
      }
      #pragma unroll
      for (int cvt = 0; cvt < 16; ++cvt) {
        #pragma unroll
        for (int r = 0; r < 4; ++r) acc[cvt][r] *= scal[r];
      }
    }
    #pragma unroll
    for (int r = 0; r < 4; ++r) {
      float p0 = __expf(s[0][r] - mrun[r]);
      float p1 = __expf(s[1][r] - mrun[r]);
      float p2 = __expf(s[2][r] - mrun[r]);
      float p3 = __expf(s[3][r] - mrun[r]);
      s[0][r] = p0; s[1][r] = p1; s[2][r] = p2; s[3][r] = p3;
      float rs = (p0 + p1) + (p2 + p3);
      rs += __shfl_xor(rs, 1);
      rs += __shfl_xor(rs, 2);
      rs += __shfl_xor(rs, 4);
      rs += __shfl_xor(rs, 8);
      lrun[r] += rs;
    }
    // ---- P: C-layout -> A-layout via per-wave LDS round-trip ----
    #pragma unroll
    for (int mt = 0; mt < 4; ++mt) {
      #pragma unroll
      for (int r = 0; r < 4; ++r)
        plds[w][4 * g + r][mt * 16 + c] = s[mt][r];
    }
    short8 pf[2];
    #pragma unroll
    for (int ks = 0; ks < 2; ++ks) {
      float pv[8];
      *(float4*)&pv[0] = *(const float4*)&plds[w][c][ks * 32 + g * 8];
      *(float4*)&pv[4] = *(const float4*)&plds[w][c][ks * 32 + g * 8 + 4];
      short8 f;
      #pragma unroll
      for (int j = 0; j < 8; ++j) f[j] = (short)f2bf(pv[j]);
      pf[ks] = f;
    }
    // ---- PV ----
    #pragma unroll
    for (int cvt = 0; cvt < 16; ++cvt) {
      const unsigned short* vrow = vtb + (size_t)(cvt * 16 + c) * MP + m0 + g * 8;
      short8 v0 = *(const short8*)(vrow);
      short8 v1 = *(const short8*)(vrow + 32);
      acc[cvt] = __builtin_amdgcn_mfma_f32_16x16x32_bf16(pf[0], v0, acc[cvt], 0, 0, 0);
      acc[cvt] = __builtin_amdgcn_mfma_f32_16x16x32_bf16(pf[1], v1, acc[cvt], 0, 0, 0);
    }
  }
  // ---- epilogue ----
  unsigned short* ab = at + ((size_t)b * NPIX + n0 + w * 16) * CV;
  #pragma unroll
  for (int r = 0; r < 4; ++r) {
    float inv = 1.0f / lrun[r];
    int row = 4 * g + r;
    #pragma unroll
    for (int cvt = 0; cvt < 16; ++cvt)
      ab[(size_t)row * CV + cvt * 16 + c] = f2bf(acc[cvt][r] * inv);
  }
}

// ---------------- MFMA output projection + bias + gating + residual ----------------
__global__ __launch_bounds__(256) void out_mfma_kernel(
    const unsigned short* __restrict__ at, const unsigned short* __restrict__ wohi,
    const float* __restrict__ bo, const float* __restrict__ hidden,
    const float* __restrict__ gating, float* __restrict__ outp)
{
  const int n0 = blockIdx.x * 64;
  const int o0 = blockIdx.y * 64;
  const int b  = blockIdx.z;
  const int t  = threadIdx.x;
  const int w    = t >> 6;
  const int lane = t & 63;
  const int c = lane & 15;
  const int g = lane >> 4;
  f32x4 acc[4];
  #pragma unroll
  for (int i = 0; i < 4; ++i) { acc[i][0]=0.f; acc[i][1]=0.f; acc[i][2]=0.f; acc[i][3]=0.f; }
  const unsigned short* ab = at + (size_t)b * NPIX * CV;
  #pragma unroll
  for (int ks = 0; ks < 8; ++ks) {
    short8 aw = *(const short8*)(wohi + (size_t)(o0 + w * 16 + c) * CV + ks * 32 + g * 8);
    #pragma unroll
    for (int nt = 0; nt < 4; ++nt) {
      short8 bv = *(const short8*)(ab + (size_t)(n0 + nt * 16 + c) * CV + ks * 32 + g * 8);
      acc[nt] = __builtin_amdgcn_mfma_f32_16x16x32_bf16(aw, bv, acc[nt], 0, 0, 0);
    }
  }
  const float gt = gating[0];
  #pragma unroll
  for (int nt = 0; nt < 4; ++nt) {
    #pragma unroll
    for (int r = 0; r < 4; ++r) {
      int oc = o0 + w * 16 + 4 * g + r;
      int n  = n0 + nt * 16 + c;
      size_t idx = ((size_t)b * C_ + oc) * NPIX + n;
      outp[idx] = hidden[idx] + gt * (acc[nt][r] + bo[oc]);
    }
  }
}

extern "C" void kernel_launch(void* const* d_in, const int* in_sizes, int n_in,
                              void* d_out, int out_size, void* d_ws, size_t ws_size,
                              hipStream_t stream)
{
  const float* hidden = (const float*)d_in[0];
  const float* Wq = (const float*)d_in[1];
  const float* Wk = (const float*)d_in[2];
  const float* Wv = (const float*)d_in[3];
  const float* Wo = (const float*)d_in[4];
  const float* bo = (const float*)d_in[5];
  const float* gating = (const float*)d_in[6];
  float* out = (float*)d_out;
  char* ws = (char*)d_ws;

  // ws layout (bytes), peak ~108.75 MB:
  //   qhi  [B][N][64]   @   0 MB (8 MB)     qlo @  8 MB
  //   khi  [B][N][64]   @  16 MB (8 MB)     klo @ 24 MB
  //   v    [B][N][256]  @  32 MB (32 MB)
  //   at   [B][N][256]  @  64 MB (32 MB)
  //   kphi [B][MP][64]  @  96 MB (2 MB)     kplo @ 98 MB
  //   vt   [B][256][MP] @ 100 MB (8 MB)
  //   weights (bf16)    @ 108 MB (768 KB)
  unsigned short* qhi  = (unsigned short*)(ws);
  unsigned short* qlo  = (unsigned short*)(ws + (8ull << 20));
  unsigned short* khi  = (unsigned short*)(ws + (16ull << 20));
  unsigned short* klo  = (unsigned short*)(ws + (24ull << 20));
  unsigned short* v    = (unsigned short*)(ws + (32ull << 20));
  unsigned short* at   = (unsigned short*)(ws + (64ull << 20));
  unsigned short* kphi = (unsigned short*)(ws + (96ull << 20));
  unsigned short* kplo = (unsigned short*)(ws + (98ull << 20));
  unsigned short* vt   = (unsigned short*)(ws + (100ull << 20));
  char* wbase = ws + (108ull << 20);
  unsigned short* wqhi = (unsigned short*)(wbase);
  unsigned short* wqlo = (unsigned short*)(wbase + (64 << 10));
  unsigned short* wkhi = (unsigned short*)(wbase + (128 << 10));
  unsigned short* wklo = (unsigned short*)(wbase + (192 << 10));
  unsigned short* wvhi = (unsigned short*)(wbase + (256 << 10));
  unsigned short* wohi = (unsigned short*)(wbase + (512 << 10));

  split_w_kernel<<<dim3((64 * 512 + 255) / 256), 256, 0, stream>>>(Wq, wqhi, wqlo, 64 * 512);
  split_w_kernel<<<dim3((64 * 512 + 255) / 256), 256, 0, stream>>>(Wk, wkhi, wklo, 64 * 512);
  split_w_kernel<<<dim3((256 * 512 + 255) / 256), 256, 0, stream>>>(Wv, wvhi, nullptr, 256 * 512);
  split_w_kernel<<<dim3((512 * 256 + 255) / 256), 256, 0, stream>>>(Wo, wohi, nullptr, 512 * 256);
  qkv_kernel<<<dim3(NPIX / 64, B_), 256, 0, stream>>>(
      hidden, wqhi, wqlo, wkhi, wklo, wvhi, qhi, qlo, khi, klo, v);
  pool_k_kernel<<<dim3((B_ * MP * CQK) / 256), 256, 0, stream>>>(khi, klo, kphi, kplo);
  pool_vt_kernel<<<dim3(MP / 64, CV / 64, B_), 256, 0, stream>>>(v, vt);
  attn_mfma_kernel<<<dim3(NPIX / 64, B_), 256, 0, stream>>>(qhi, qlo, kphi, kplo, vt, at);
  out_mfma_kernel<<<dim3(NPIX / 64, C_ / 64, B_), 256, 0, stream>>>(at, wohi, bo, hidden, gating, out);
}